// Round 2
// baseline (882.783 us; speedup 1.0000x reference)
//
#include <hip/hip_runtime.h>
#include <math.h>

// Problem constants (fixed by reference): B=4, C=256, C8=32, N=H*W=4096.
// ws layout: proj y[b][r][n], r: 0..31=q, 32..63=k, 64..319=v  (20.97 MB)

#define F4(p)  (*reinterpret_cast<float4*>(p))
#define CF4(p) (*reinterpret_cast<const float4*>(p))

// ---------------------------------------------------------------------------
// Projection: y[b][r][n] = sum_c Wr[c] * x[b][c][n] + bias_r   (one fused GEMM
// over the 320 concatenated output rows). x tile staged once per block ->
// x read exactly once from HBM. Block: 256 thr, tile 320d x 64n, K=256.
// ---------------------------------------------------------------------------
__global__ __launch_bounds__(256) void proj_kernel(
    const float* __restrict__ x,
    const float* __restrict__ wq, const float* __restrict__ bq,
    const float* __restrict__ wk, const float* __restrict__ bk,
    const float* __restrict__ wv, const float* __restrict__ bv,
    float* __restrict__ y)
{
    __shared__ float Xt[64][260];   // [n][c], pad 260 -> conflict-free b128 reads
    const int t   = threadIdx.x;
    const int blk = blockIdx.x;     // 256 blocks = 4 b * 64 n-tiles
    const int b   = blk >> 6;
    const int n0  = (blk & 63) * 64;

    {   // stage x[b][:, n0..n0+63] transposed
        const int tn4 = (t & 15) * 4;
        const int c0  = t >> 4;
        #pragma unroll
        for (int cc = 0; cc < 16; ++cc) {
            const int c = c0 + (cc << 4);
            const float4 xv = CF4(&x[(((size_t)b * 256 + c) << 12) + n0 + tn4]);
            Xt[tn4 + 0][c] = xv.x;
            Xt[tn4 + 1][c] = xv.y;
            Xt[tn4 + 2][c] = xv.z;
            Xt[tn4 + 3][c] = xv.w;
        }
    }
    __syncthreads();

    const int td = t >> 4;   // 0..15
    const int tn = t & 15;   // 0..15

    for (int g = 0; g < 5; ++g) {           // 5 groups of 64 output rows
        const int d0 = g * 64;
        float acc[4][4];
        #pragma unroll
        for (int i = 0; i < 4; ++i)
            #pragma unroll
            for (int j = 0; j < 4; ++j) acc[i][j] = 0.f;

        const float* wrow[4];
        float bias[4];
        #pragma unroll
        for (int dd = 0; dd < 4; ++dd) {
            const int rr = d0 + td + (dd << 4);
            if (rr < 32)      { wrow[dd] = wq + rr * 256;        bias[dd] = bq[rr]; }
            else if (rr < 64) { wrow[dd] = wk + (rr - 32) * 256; bias[dd] = bk[rr - 32]; }
            else              { wrow[dd] = wv + (rr - 64) * 256; bias[dd] = bv[rr - 64]; }
        }

        for (int c = 0; c < 256; c += 4) {
            float4 w4[4];
            #pragma unroll
            for (int dd = 0; dd < 4; ++dd) w4[dd] = CF4(&wrow[dd][c]);
            #pragma unroll
            for (int nn = 0; nn < 4; ++nn) {
                const float4 xv = CF4(&Xt[tn + (nn << 4)][c]);
                #pragma unroll
                for (int dd = 0; dd < 4; ++dd) {
                    acc[dd][nn] += w4[dd].x * xv.x + w4[dd].y * xv.y
                                 + w4[dd].z * xv.z + w4[dd].w * xv.w;
                }
            }
        }
        #pragma unroll
        for (int dd = 0; dd < 4; ++dd) {
            const int rr = d0 + td + (dd << 4);
            #pragma unroll
            for (int nn = 0; nn < 4; ++nn)
                y[((size_t)b * 320 + rr) * 4096 + n0 + tn + (nn << 4)]
                    = acc[dd][nn] + bias[dd];
        }
    }
}

// ---------------------------------------------------------------------------
// Flash attention, fp32. Block = 256 thr (4 waves), Tq=64, Tk=64.
// Grid = 256 (= 1 block/CU). Online softmax: per-row (m,l) replicated in regs
// across the 4 waves (deterministic identical values). PV: thread owns
// 8q x 8e micro-tile, q strided by 8 / e strided by 32 -> all b128 LDS reads
// conflict-free (pads of 68 floats; rows 1 apart = 4 banks apart, 8 distinct
// float4 addrs per wave cover all 32 banks once, 8-way broadcast).
// ---------------------------------------------------------------------------
__global__ __launch_bounds__(256) void attn_kernel(
    const float* __restrict__ y,
    const float* __restrict__ x,
    const float* __restrict__ gamma,
    float* __restrict__ out)
{
    __shared__ float Qt[32][68];        // [d][i]
    __shared__ float Kt[32][68];        // [d][j]
    __shared__ float Vt[256][68];       // [e][j]
    __shared__ float Ps[64][68];        // S then P, [i][j]
    __shared__ float red_max[4][64];
    __shared__ float red_sum[4][64];
    __shared__ float f_sh[64];
    __shared__ float l_sh[64];

    const int t   = threadIdx.x;
    const int blk = blockIdx.x;
    // XCD swizzle: blocks on XCD x (round-robin blk%8) all take batch x>>1 ->
    // per-XCD K/V working set = one batch (~5.25 MB ~= one L2). Perf-only.
    const int e8 = blk & 7;
    const int b  = e8 >> 1;
    const int it = (blk >> 3) + ((e8 & 1) << 5);
    const int i0 = it << 6;

    const size_t ybase = (size_t)b * 320 * 4096;

    {   // stage Q tile (once per block)
        const int i4 = (t & 15) << 2;
        const int d0 = t >> 4;
        #pragma unroll
        for (int p = 0; p < 2; ++p) {
            const int d = d0 + (p << 4);
            F4(&Qt[d][i4]) = CF4(&y[ybase + (size_t)d * 4096 + i0 + i4]);
        }
    }

    float m_run = -INFINITY;
    float l_run = 0.f;
    float acc[8][8];
    #pragma unroll
    for (int i = 0; i < 8; ++i)
        #pragma unroll
        for (int j = 0; j < 8; ++j) acc[i][j] = 0.f;

    const int r  = t & 63;   // softmax stats row (replicated x4 waves)
    const int gq = t >> 6;   // stats quarter of j
    const int oq = t & 7;    // PV owner: queries  oq + 8*qq
    const int oe = t >> 3;   // PV owner: channels oe + 32*ee

    for (int jt = 0; jt < 64; ++jt) {
        const int j0 = jt << 6;
        __syncthreads();                       // Kt/Vt/Ps safe to overwrite
        {   // stage K and V tiles
            const int i4 = (t & 15) << 2;
            const int d0 = t >> 4;
            #pragma unroll
            for (int p = 0; p < 2; ++p) {
                const int d = d0 + (p << 4);
                F4(&Kt[d][i4]) = CF4(&y[ybase + (size_t)(32 + d) * 4096 + j0 + i4]);
            }
            #pragma unroll
            for (int ee = 0; ee < 16; ++ee) {
                const int e = d0 + (ee << 4);
                F4(&Vt[e][i4]) = CF4(&y[ybase + (size_t)(64 + e) * 4096 + j0 + i4]);
            }
        }
        {   // S tile: 4x4 micro-tile per thread
            const int si0 = (t >> 4) << 2;
            const int sj0 = (t & 15) << 2;
            float s[4][4];
            #pragma unroll
            for (int i = 0; i < 4; ++i)
                #pragma unroll
                for (int j = 0; j < 4; ++j) s[i][j] = 0.f;
            #pragma unroll 8
            for (int d = 0; d < 32; ++d) {
                const float4 q4 = CF4(&Qt[d][si0]);
                const float4 k4 = CF4(&Kt[d][sj0]);
                s[0][0] += q4.x * k4.x; s[0][1] += q4.x * k4.y; s[0][2] += q4.x * k4.z; s[0][3] += q4.x * k4.w;
                s[1][0] += q4.y * k4.x; s[1][1] += q4.y * k4.y; s[1][2] += q4.y * k4.z; s[1][3] += q4.y * k4.w;
                s[2][0] += q4.z * k4.x; s[2][1] += q4.z * k4.y; s[2][2] += q4.z * k4.z; s[2][3] += q4.z * k4.w;
                s[3][0] += q4.w * k4.x; s[3][1] += q4.w * k4.y; s[3][2] += q4.w * k4.z; s[3][3] += q4.w * k4.w;
            }
            #pragma unroll
            for (int i = 0; i < 4; ++i)
                F4(&Ps[si0 + i][sj0]) = make_float4(s[i][0], s[i][1], s[i][2], s[i][3]);
        }
        __syncthreads();                       // S complete
        {   // B1: partial row max over this wave's quarter
            float pm = -INFINITY;
            #pragma unroll
            for (int c = 0; c < 4; ++c) {
                const float4 v = CF4(&Ps[r][(gq << 4) + (c << 2)]);
                pm = fmaxf(pm, fmaxf(fmaxf(v.x, v.y), fmaxf(v.z, v.w)));
            }
            red_max[gq][r] = pm;
        }
        __syncthreads();
        float m_new, fac;
        {   // B2: new max, exponentiate own quarter in place, partial sum
            const float mt = fmaxf(fmaxf(red_max[0][r], red_max[1][r]),
                                   fmaxf(red_max[2][r], red_max[3][r]));
            m_new = fmaxf(m_run, mt);
            fac   = __expf(m_run - m_new);     // m_run=-inf first tile -> 0
            float psum = 0.f;
            #pragma unroll
            for (int c = 0; c < 4; ++c) {
                float4 v = CF4(&Ps[r][(gq << 4) + (c << 2)]);
                v.x = __expf(v.x - m_new); v.y = __expf(v.y - m_new);
                v.z = __expf(v.z - m_new); v.w = __expf(v.w - m_new);
                psum += v.x + v.y + v.z + v.w;
                F4(&Ps[r][(gq << 4) + (c << 2)]) = v;
            }
            red_sum[gq][r] = psum;
            if (t < 64) f_sh[r] = fac;         // single writer per row
        }
        __syncthreads();
        {   // B3: fold tile into running (m,l)  (replicated, deterministic)
            const float rowsum = red_sum[0][r] + red_sum[1][r]
                               + red_sum[2][r] + red_sum[3][r];
            l_run = l_run * fac + rowsum;
            m_run = m_new;
        }
        {   // PV: rescale acc by f(q), then accumulate P @ V^T
            float fq[8];
            #pragma unroll
            for (int qq = 0; qq < 8; ++qq) fq[qq] = f_sh[oq + (qq << 3)];
            #pragma unroll
            for (int qq = 0; qq < 8; ++qq)
                #pragma unroll
                for (int ee = 0; ee < 8; ++ee) acc[qq][ee] *= fq[qq];
            #pragma unroll 2
            for (int jc = 0; jc < 64; jc += 4) {
                float4 p4[8], v4[8];
                #pragma unroll
                for (int qq = 0; qq < 8; ++qq) p4[qq] = CF4(&Ps[oq + (qq << 3)][jc]);
                #pragma unroll
                for (int ee = 0; ee < 8; ++ee) v4[ee] = CF4(&Vt[oe + (ee << 5)][jc]);
                #pragma unroll
                for (int qq = 0; qq < 8; ++qq)
                    #pragma unroll
                    for (int ee = 0; ee < 8; ++ee)
                        acc[qq][ee] += p4[qq].x * v4[ee].x + p4[qq].y * v4[ee].y
                                     + p4[qq].z * v4[ee].z + p4[qq].w * v4[ee].w;
            }
        }
    }

    __syncthreads();
    if (t < 64) l_sh[t] = l_run;
    __syncthreads();

    const float gv = gamma[0];
    float linv[8];
    #pragma unroll
    for (int qq = 0; qq < 8; ++qq) linv[qq] = 1.f / l_sh[oq + (qq << 3)];
    #pragma unroll
    for (int qq = 0; qq < 8; ++qq) {
        const int i = i0 + oq + (qq << 3);
        #pragma unroll
        for (int ee = 0; ee < 8; ++ee) {
            const int e = oe + (ee << 5);
            const size_t idx = ((size_t)b * 256 + e) * 4096 + i;
            out[idx] = gv * acc[qq][ee] * linv[qq] + x[idx];
        }
    }
}

extern "C" void kernel_launch(void* const* d_in, const int* in_sizes, int n_in,
                              void* d_out, int out_size, void* d_ws, size_t ws_size,
                              hipStream_t stream) {
    const float* x     = (const float*)d_in[0];
    const float* wq    = (const float*)d_in[1];
    const float* bq    = (const float*)d_in[2];
    const float* wk    = (const float*)d_in[3];
    const float* bk    = (const float*)d_in[4];
    const float* wv    = (const float*)d_in[5];
    const float* bv    = (const float*)d_in[6];
    const float* gamma = (const float*)d_in[7];
    float* out = (float*)d_out;
    float* y   = (float*)d_ws;   // 4*320*4096 floats = 20.97 MB

    proj_kernel<<<256, 256, 0, stream>>>(x, wq, bq, wk, bk, wv, bv, y);
    attn_kernel<<<256, 256, 0, stream>>>(y, x, gamma, out);
}

// Round 4
// 402.940 us; speedup vs baseline: 2.1909x; 2.1909x over previous
//
#include <hip/hip_runtime.h>
#include <math.h>

// B=4, C=256, C8=32, N=4096. ws (bf16/ushort elems):
//   qth[b][n][32], qtl, kth, ktl   (4 x 524288)
//   vh[b][e][n], vl                (2 x 4194304)      total 20.97 MB
typedef __attribute__((ext_vector_type(8))) short bf16x8;
typedef __attribute__((ext_vector_type(4))) float f32x4;
typedef unsigned short ushort;
typedef unsigned int uint;

#define CF4(p) (*reinterpret_cast<const float4*>(p))

__device__ __forceinline__ ushort f2bf(float f) {
    uint u = __float_as_uint(f);
    return (ushort)((u + 0x7FFFu + ((u >> 16) & 1u)) >> 16);   // RNE
}
__device__ __forceinline__ float bf2f(ushort h) {
    return __uint_as_float(((uint)h) << 16);
}

// ---------------------------------------------------------------------------
// Projection GEMM (fp32) -> bf16 hi/lo outputs in MFMA-ready layouts.
// ---------------------------------------------------------------------------
__global__ __launch_bounds__(256) void proj_kernel(
    const float* __restrict__ x,
    const float* __restrict__ wq, const float* __restrict__ bq,
    const float* __restrict__ wk, const float* __restrict__ bk,
    const float* __restrict__ wv, const float* __restrict__ bv,
    ushort* __restrict__ ws)
{
    ushort* qth = ws;
    ushort* qtl = qth + 524288;
    ushort* kth = qtl + 524288;
    ushort* ktl = kth + 524288;
    ushort* vhp = ktl + 524288;
    ushort* vlp = vhp + 4194304;

    __shared__ float Xt[64][260];
    const int t   = threadIdx.x;
    const int blk = blockIdx.x;
    const int b   = blk >> 6;
    const int n0  = (blk & 63) * 64;

    {
        const int tn4 = (t & 15) * 4;
        const int c0  = t >> 4;
        #pragma unroll
        for (int cc = 0; cc < 16; ++cc) {
            const int c = c0 + (cc << 4);
            const float4 xv = CF4(&x[(((size_t)b * 256 + c) << 12) + n0 + tn4]);
            Xt[tn4 + 0][c] = xv.x;
            Xt[tn4 + 1][c] = xv.y;
            Xt[tn4 + 2][c] = xv.z;
            Xt[tn4 + 3][c] = xv.w;
        }
    }
    __syncthreads();

    const int td = t >> 4;
    const int tn = t & 15;

    for (int g = 0; g < 5; ++g) {
        const int d0 = g * 64;
        float acc[4][4];
        #pragma unroll
        for (int i = 0; i < 4; ++i)
            #pragma unroll
            for (int j = 0; j < 4; ++j) acc[i][j] = 0.f;

        const float* wrow[4];
        float bias[4];
        #pragma unroll
        for (int dd = 0; dd < 4; ++dd) {
            const int rr = d0 + td + (dd << 4);
            if (rr < 32)      { wrow[dd] = wq + rr * 256;        bias[dd] = bq[rr]; }
            else if (rr < 64) { wrow[dd] = wk + (rr - 32) * 256; bias[dd] = bk[rr - 32]; }
            else              { wrow[dd] = wv + (rr - 64) * 256; bias[dd] = bv[rr - 64]; }
        }

        for (int c = 0; c < 256; c += 4) {
            float4 w4[4];
            #pragma unroll
            for (int dd = 0; dd < 4; ++dd) w4[dd] = CF4(&wrow[dd][c]);
            #pragma unroll
            for (int nn = 0; nn < 4; ++nn) {
                const float4 xv = CF4(&Xt[tn + (nn << 4)][c]);
                #pragma unroll
                for (int dd = 0; dd < 4; ++dd) {
                    acc[dd][nn] += w4[dd].x * xv.x + w4[dd].y * xv.y
                                 + w4[dd].z * xv.z + w4[dd].w * xv.w;
                }
            }
        }
        #pragma unroll
        for (int dd = 0; dd < 4; ++dd) {
            const int rr = d0 + td + (dd << 4);
            #pragma unroll
            for (int nn = 0; nn < 4; ++nn) {
                const int n = n0 + tn + (nn << 4);
                const float val = acc[dd][nn] + bias[dd];
                const ushort h  = f2bf(val);
                const ushort lo = f2bf(val - bf2f(h));
                if (rr < 32) {
                    const size_t o = ((size_t)(b * 4096 + n)) * 32 + rr;
                    qth[o] = h; qtl[o] = lo;
                } else if (rr < 64) {
                    const size_t o = ((size_t)(b * 4096 + n)) * 32 + (rr - 32);
                    kth[o] = h; ktl[o] = lo;
                } else {
                    const size_t o = ((size_t)(b * 256 + (rr - 64))) * 4096 + n;
                    vhp[o] = h; vlp[o] = lo;
                }
            }
        }
    }
}

// ---------------------------------------------------------------------------
// Flash attention via bf16 MFMA (hi/lo split, 3-term products).
// Block = 256 thr (4 waves), Tq=64 (grid 256). Wave w: S^T for i-strip w
// (full 64 j in-lane -> in-register softmax), PV for e-strip w (64 chans).
// P shared via XOR-swizzled LDS (hi/lo bf16). K/V frags straight from L2.
// ---------------------------------------------------------------------------
__global__ __launch_bounds__(256, 1) void attn_kernel(
    const ushort* __restrict__ ws,
    const float* __restrict__ x,
    const float* __restrict__ gamma,
    float* __restrict__ out)
{
    const ushort* qth = ws;
    const ushort* qtl = qth + 524288;
    const ushort* kth = qtl + 524288;
    const ushort* ktl = kth + 524288;
    const ushort* vhp = ktl + 524288;
    const ushort* vlp = vhp + 4194304;

    __shared__ __align__(16) ushort Ph[4096];   // [i][j^((i&7)<<3)]
    __shared__ __align__(16) ushort Pl[4096];
    __shared__ float fac_sh[64];
    __shared__ float l_sh[64];

    const int t    = threadIdx.x;
    const int w    = t >> 6;
    const int lane = t & 63;
    const int m    = lane & 15;
    const int gr   = lane >> 4;

    const int blk = blockIdx.x;              // XCD swizzle: batch per XCD-pair
    const int e8  = blk & 7;
    const int b   = e8 >> 1;
    const int i0  = ((blk >> 3) + ((e8 & 1) << 5)) << 6;

    const size_t qkbase = (size_t)b * 4096 * 32;
    const size_t vbase  = (size_t)b * 256 * 4096;

    // Q B-fragment for this wave's i-strip (constant over j loop)
    const int iq = i0 + w * 16 + m;
    const bf16x8 qbh = *(const bf16x8*)(qth + qkbase + (size_t)iq * 32 + 8 * gr);
    const bf16x8 qbl = *(const bf16x8*)(qtl + qkbase + (size_t)iq * 32 + 8 * gr);

    f32x4 accv[4][4];                        // [mf(e)][f(i)] — static indexing only
    #pragma unroll
    for (int a = 0; a < 4; ++a)
        #pragma unroll
        for (int c = 0; c < 4; ++c) accv[a][c] = f32x4{0.f, 0.f, 0.f, 0.f};

    float m_run = -INFINITY, l_run = 0.f;
    const int irow = w * 16 + m;             // local i this lane's stats cover

    for (int jt = 0; jt < 64; ++jt) {
        const int j0 = jt << 6;

        // --- K A-fragments (rows j0+mf*16+m, d-slice 8*gr) ---
        bf16x8 kh[4], kl[4];
        #pragma unroll
        for (int mf = 0; mf < 4; ++mf) {
            const size_t ko = qkbase + (size_t)(j0 + mf * 16 + m) * 32 + 8 * gr;
            kh[mf] = *(const bf16x8*)(kth + ko);
            kl[mf] = *(const bf16x8*)(ktl + ko);
        }
        // --- S^T = K·Q (3-term hi/lo) ---
        f32x4 st[4];
        #pragma unroll
        for (int mf = 0; mf < 4; ++mf) {
            f32x4 a = {0.f, 0.f, 0.f, 0.f};
            a = __builtin_amdgcn_mfma_f32_16x16x32_bf16(kh[mf], qbh, a, 0, 0, 0);
            a = __builtin_amdgcn_mfma_f32_16x16x32_bf16(kh[mf], qbl, a, 0, 0, 0);
            a = __builtin_amdgcn_mfma_f32_16x16x32_bf16(kl[mf], qbh, a, 0, 0, 0);
            st[mf] = a;
        }
        // --- online softmax (in-lane 16 + shfl over 4 j-replica groups) ---
        float tm = st[0][0];
        #pragma unroll
        for (int mf = 0; mf < 4; ++mf)
            #pragma unroll
            for (int r = 0; r < 4; ++r) tm = fmaxf(tm, st[mf][r]);
        tm = fmaxf(tm, __shfl_xor(tm, 16));
        tm = fmaxf(tm, __shfl_xor(tm, 32));
        const float m_new = fmaxf(m_run, tm);
        const float fac   = __expf(m_run - m_new);
        float p[4][4];
        float ts = 0.f;
        #pragma unroll
        for (int mf = 0; mf < 4; ++mf)
            #pragma unroll
            for (int r = 0; r < 4; ++r) {
                p[mf][r] = __expf(st[mf][r] - m_new);
                ts += p[mf][r];
            }
        ts += __shfl_xor(ts, 16);
        ts += __shfl_xor(ts, 32);
        l_run = l_run * fac + ts;
        m_run = m_new;

        // --- write P hi/lo (r-quads packed, XOR-swizzled) + fac ---
        #pragma unroll
        for (int mf = 0; mf < 4; ++mf) {
            const int j    = mf * 16 + 4 * gr;
            const int addr = irow * 64 + (j ^ ((irow & 7) << 3));
            ushort h0 = f2bf(p[mf][0]), h1 = f2bf(p[mf][1]);
            ushort h2 = f2bf(p[mf][2]), h3 = f2bf(p[mf][3]);
            ushort l0 = f2bf(p[mf][0] - bf2f(h0)), l1 = f2bf(p[mf][1] - bf2f(h1));
            ushort l2 = f2bf(p[mf][2] - bf2f(h2)), l3 = f2bf(p[mf][3] - bf2f(h3));
            *reinterpret_cast<uint2*>(&Ph[addr]) =
                make_uint2((uint)h0 | ((uint)h1 << 16), (uint)h2 | ((uint)h3 << 16));
            *reinterpret_cast<uint2*>(&Pl[addr]) =
                make_uint2((uint)l0 | ((uint)l1 << 16), (uint)l2 | ((uint)l3 << 16));
        }
        if (gr == 0) fac_sh[irow] = fac;
        __syncthreads();                      // P + fac ready

        // --- rescale accumulators by per-i-strip factor ---
        float fc[4];
        #pragma unroll
        for (int f = 0; f < 4; ++f) fc[f] = fac_sh[f * 16 + m];
        #pragma unroll
        for (int mf = 0; mf < 4; ++mf)
            #pragma unroll
            for (int f = 0; f < 4; ++f)
                #pragma unroll
                for (int r = 0; r < 4; ++r) accv[mf][f][r] *= fc[f];

        // --- PV: out[e][i] += V[e][j] P[i][j]  (3-term hi/lo) ---
        #pragma unroll
        for (int ks = 0; ks < 2; ++ks) {
            bf16x8 pbh[4], pbl[4];
            #pragma unroll
            for (int f = 0; f < 4; ++f) {
                const int i_   = f * 16 + m;
                const int j    = ks * 32 + 8 * gr;
                const int addr = i_ * 64 + (j ^ ((i_ & 7) << 3));
                pbh[f] = *reinterpret_cast<const bf16x8*>(&Ph[addr]);
                pbl[f] = *reinterpret_cast<const bf16x8*>(&Pl[addr]);
            }
            #pragma unroll
            for (int mf = 0; mf < 4; ++mf) {
                const size_t vo = vbase + (size_t)(w * 64 + mf * 16 + m) * 4096
                                + j0 + ks * 32 + 8 * gr;
                const bf16x8 vah = *(const bf16x8*)(vhp + vo);
                const bf16x8 val = *(const bf16x8*)(vlp + vo);
                #pragma unroll
                for (int f = 0; f < 4; ++f) {
                    accv[mf][f] = __builtin_amdgcn_mfma_f32_16x16x32_bf16(vah, pbh[f], accv[mf][f], 0, 0, 0);
                    accv[mf][f] = __builtin_amdgcn_mfma_f32_16x16x32_bf16(vah, pbl[f], accv[mf][f], 0, 0, 0);
                    accv[mf][f] = __builtin_amdgcn_mfma_f32_16x16x32_bf16(val, pbh[f], accv[mf][f], 0, 0, 0);
                }
            }
        }
        __syncthreads();                      // PV done reading Ph/Pl
    }

    if (gr == 0) l_sh[irow] = l_run;
    __syncthreads();

    const float gv = gamma[0];
    float sc[4];
    #pragma unroll
    for (int f = 0; f < 4; ++f) sc[f] = gv / l_sh[f * 16 + m];
    #pragma unroll
    for (int mf = 0; mf < 4; ++mf)
        #pragma unroll
        for (int f = 0; f < 4; ++f)
            #pragma unroll
            for (int r = 0; r < 4; ++r) {
                const int e = w * 64 + mf * 16 + 4 * gr + r;
                const int i = i0 + f * 16 + m;
                const size_t idx = ((size_t)b * 256 + e) * 4096 + i;
                out[idx] = accv[mf][f][r] * sc[f] + x[idx];
            }
}

extern "C" void kernel_launch(void* const* d_in, const int* in_sizes, int n_in,
                              void* d_out, int out_size, void* d_ws, size_t ws_size,
                              hipStream_t stream) {
    const float* x     = (const float*)d_in[0];
    const float* wq    = (const float*)d_in[1];
    const float* bq    = (const float*)d_in[2];
    const float* wk    = (const float*)d_in[3];
    const float* bk    = (const float*)d_in[4];
    const float* bv    = (const float*)d_in[6];
    const float* wv    = (const float*)d_in[5];
    const float* gamma = (const float*)d_in[7];
    float* out  = (float*)d_out;
    ushort* ws  = (ushort*)d_ws;    // 10.5M ushorts = 20.97 MB

    proj_kernel<<<256, 256, 0, stream>>>(x, wq, bq, wk, bk, wv, bv, ws);
    attn_kernel<<<256, 256, 0, stream>>>(ws, x, gamma, out);
}

// Round 10
// 360.295 us; speedup vs baseline: 2.4502x; 1.1184x over previous
//
#include <hip/hip_runtime.h>
#include <math.h>

// B=4, C=256, C8=32, N=4096. ws (bf16/ushort elems):
//   qth[b][n][32], qtl, kth, ktl   (4 x 524288)
//   vh[b][e][n], vl                (2 x 4194304)      total 20.97 MB
typedef __attribute__((ext_vector_type(8))) short bf16x8;
typedef __attribute__((ext_vector_type(4))) float f32x4;
typedef unsigned short ushort;
typedef unsigned int uint;

#define F4(p)  (*reinterpret_cast<float4*>(p))
#define CF4(p) (*reinterpret_cast<const float4*>(p))

__device__ __forceinline__ ushort f2bf(float f) {
    uint u = __float_as_uint(f);
    return (ushort)((u + 0x7FFFu + ((u >> 16) & 1u)) >> 16);   // RNE
}
__device__ __forceinline__ float bf2f(ushort h) {
    return __uint_as_float(((uint)h) << 16);
}

// ---------------------------------------------------------------------------
// Projection GEMM (fp32) -> bf16 hi/lo, MFMA-ready layouts.
// Outputs staged in LDS per 64-row group, flushed as coalesced 16B stores.
// ---------------------------------------------------------------------------
__global__ __launch_bounds__(256) void proj_kernel(
    const float* __restrict__ x,
    const float* __restrict__ wq, const float* __restrict__ bq,
    const float* __restrict__ wk, const float* __restrict__ bk,
    const float* __restrict__ wv, const float* __restrict__ bv,
    ushort* __restrict__ ws)
{
    ushort* qth = ws;
    ushort* qtl = qth + 524288;
    ushort* kth = qtl + 524288;
    ushort* ktl = kth + 524288;
    ushort* vhp = ktl + 524288;
    ushort* vlp = vhp + 4194304;

    __shared__ float Xt[64][260];
    __shared__ __align__(16) ushort Oh[4096];
    __shared__ __align__(16) ushort Ol[4096];

    const int t   = threadIdx.x;
    const int blk = blockIdx.x;
    const int b   = blk >> 6;
    const int n0  = (blk & 63) * 64;

    {   // stage x[b][:, n0..n0+63] transposed
        const int tn4 = (t & 15) * 4;
        const int c0  = t >> 4;
        #pragma unroll
        for (int cc = 0; cc < 16; ++cc) {
            const int c = c0 + (cc << 4);
            const float4 xv = CF4(&x[(((size_t)b * 256 + c) << 12) + n0 + tn4]);
            Xt[tn4 + 0][c] = xv.x;
            Xt[tn4 + 1][c] = xv.y;
            Xt[tn4 + 2][c] = xv.z;
            Xt[tn4 + 3][c] = xv.w;
        }
    }
    __syncthreads();

    const int td = t >> 4;
    const int tn = t & 15;

    for (int g = 0; g < 5; ++g) {
        const int d0 = g * 64;
        float acc[4][4];
        #pragma unroll
        for (int i = 0; i < 4; ++i)
            #pragma unroll
            for (int j = 0; j < 4; ++j) acc[i][j] = 0.f;

        const float* wrow[4];
        float bias[4];
        #pragma unroll
        for (int dd = 0; dd < 4; ++dd) {
            const int rr = d0 + td + (dd << 4);
            if (rr < 32)      { wrow[dd] = wq + rr * 256;        bias[dd] = bq[rr]; }
            else if (rr < 64) { wrow[dd] = wk + (rr - 32) * 256; bias[dd] = bk[rr - 32]; }
            else              { wrow[dd] = wv + (rr - 64) * 256; bias[dd] = bv[rr - 64]; }
        }

        for (int c = 0; c < 256; c += 4) {
            float4 w4[4];
            #pragma unroll
            for (int dd = 0; dd < 4; ++dd) w4[dd] = CF4(&wrow[dd][c]);
            #pragma unroll
            for (int nn = 0; nn < 4; ++nn) {
                const float4 xv = CF4(&Xt[tn + (nn << 4)][c]);
                #pragma unroll
                for (int dd = 0; dd < 4; ++dd) {
                    acc[dd][nn] += w4[dd].x * xv.x + w4[dd].y * xv.y
                                 + w4[dd].z * xv.z + w4[dd].w * xv.w;
                }
            }
        }

        // stage hi/lo into LDS (layout matches the flat global layout)
        #pragma unroll
        for (int dd = 0; dd < 4; ++dd) {
            const int rr = d0 + td + (dd << 4);
            #pragma unroll
            for (int nn = 0; nn < 4; ++nn) {
                const int nl  = tn + (nn << 4);
                const float val = acc[dd][nn] + bias[dd];
                const ushort h  = f2bf(val);
                const ushort lo = f2bf(val - bf2f(h));
                int o;
                if (g == 0) o = (rr < 32) ? nl * 32 + rr : 2048 + nl * 32 + (rr - 32);
                else        o = (rr - d0) * 64 + nl;
                Oh[o] = h; Ol[o] = lo;
            }
        }
        __syncthreads();     // LDS tile complete

        // flush: 16B coalesced stores
        if (g == 0) {
            const size_t qb = ((size_t)(b * 4096 + n0)) * 32;
            #pragma unroll
            for (int s = 0; s < 2; ++s) {
                const int o = t * 16 + s * 8;
                const float4 vh = F4(&Oh[o]);
                const float4 vl = F4(&Ol[o]);
                if (o < 2048) {
                    F4(&qth[qb + o]) = vh;
                    F4(&qtl[qb + o]) = vl;
                } else {
                    F4(&kth[qb + o - 2048]) = vh;
                    F4(&ktl[qb + o - 2048]) = vl;
                }
            }
        } else {
            const size_t vb = ((size_t)(b * 256 + (g - 1) * 64)) * 4096 + n0;
            #pragma unroll
            for (int s = 0; s < 2; ++s) {
                const int o  = t * 16 + s * 8;
                const size_t ga = vb + (size_t)(o >> 6) * 4096 + (o & 63);
                F4(&vhp[ga]) = F4(&Oh[o]);
                F4(&vlp[ga]) = F4(&Ol[o]);
            }
        }
        __syncthreads();     // flush done before next group's LDS writes
    }
}

// ---------------------------------------------------------------------------
// Flash attention via bf16 MFMA (hi/lo split, 3-term products).
// Grid 512: (b, i-tile, e-half). Block = 256 thr (4 waves), Tq=64.
// Wave w: S^T for i-strip w (full 64 j in-lane -> in-register softmax);
// PV for 32 channels e in [ehalf*128 + w*32, +32). QK^T+softmax duplicated
// across the 2 e-halves (~11% MFMA overhead) to get 2 blocks/CU.
// ---------------------------------------------------------------------------
__global__ __launch_bounds__(256, 2) void attn_kernel(
    const ushort* __restrict__ ws,
    const float* __restrict__ x,
    const float* __restrict__ gamma,
    float* __restrict__ out)
{
    const ushort* qth = ws;
    const ushort* qtl = qth + 524288;
    const ushort* kth = qtl + 524288;
    const ushort* ktl = kth + 524288;
    const ushort* vhp = ktl + 524288;
    const ushort* vlp = vhp + 4194304;

    __shared__ __align__(16) ushort Ph[4096];   // [i][j^((i&7)<<3)]
    __shared__ __align__(16) ushort Pl[4096];
    __shared__ float fac_sh[64];
    __shared__ float l_sh[64];

    const int t    = threadIdx.x;
    const int w    = t >> 6;
    const int lane = t & 63;
    const int m    = lane & 15;
    const int gr   = lane >> 4;

    // XCD swizzle: e8 = blk&7 -> XCD; batch per XCD-pair; the two e-halves of
    // one (b,it) share an XCD (same K/Q lines in that L2).
    const int blk = blockIdx.x;
    const int e8  = blk & 7;
    const int g_  = blk >> 3;                // 0..63
    const int b   = e8 >> 1;
    const int i0  = ((g_ & 31) + ((e8 & 1) << 5)) << 6;
    const int ebase = ((g_ >> 5) << 7) + w * 32;   // this wave's 32 channels

    const size_t qkbase = (size_t)b * 4096 * 32;
    const size_t vbase  = (size_t)b * 256 * 4096;

    // Q B-fragment for this wave's i-strip (constant over j loop)
    const int iq = i0 + w * 16 + m;
    const bf16x8 qbh = *(const bf16x8*)(qth + qkbase + (size_t)iq * 32 + 8 * gr);
    const bf16x8 qbl = *(const bf16x8*)(qtl + qkbase + (size_t)iq * 32 + 8 * gr);

    f32x4 accv[2][4];                        // [mf(e)][f(i)] — static indexing only
    #pragma unroll
    for (int a = 0; a < 2; ++a)
        #pragma unroll
        for (int c = 0; c < 4; ++c) accv[a][c] = f32x4{0.f, 0.f, 0.f, 0.f};

    float m_run = -INFINITY, l_run = 0.f;
    const int irow = w * 16 + m;             // local i this lane's stats cover

    for (int jt = 0; jt < 64; ++jt) {
        const int j0 = jt << 6;

        // --- K A-fragments (rows j0+mf*16+m, d-slice 8*gr) ---
        bf16x8 kh[4], kl[4];
        #pragma unroll
        for (int mf = 0; mf < 4; ++mf) {
            const size_t ko = qkbase + (size_t)(j0 + mf * 16 + m) * 32 + 8 * gr;
            kh[mf] = *(const bf16x8*)(kth + ko);
            kl[mf] = *(const bf16x8*)(ktl + ko);
        }
        // --- S^T = K·Q (3-term hi/lo) ---
        f32x4 st[4];
        #pragma unroll
        for (int mf = 0; mf < 4; ++mf) {
            f32x4 a = {0.f, 0.f, 0.f, 0.f};
            a = __builtin_amdgcn_mfma_f32_16x16x32_bf16(kh[mf], qbh, a, 0, 0, 0);
            a = __builtin_amdgcn_mfma_f32_16x16x32_bf16(kh[mf], qbl, a, 0, 0, 0);
            a = __builtin_amdgcn_mfma_f32_16x16x32_bf16(kl[mf], qbh, a, 0, 0, 0);
            st[mf] = a;
        }
        // --- online softmax (in-lane 16 + shfl over 4 j-replica groups) ---
        float tm = st[0][0];
        #pragma unroll
        for (int mf = 0; mf < 4; ++mf)
            #pragma unroll
            for (int r = 0; r < 4; ++r) tm = fmaxf(tm, st[mf][r]);
        tm = fmaxf(tm, __shfl_xor(tm, 16));
        tm = fmaxf(tm, __shfl_xor(tm, 32));
        const float m_new = fmaxf(m_run, tm);
        const float fac   = __expf(m_run - m_new);     // -inf first tile -> 0
        float p[4][4];
        float ts = 0.f;
        #pragma unroll
        for (int mf = 0; mf < 4; ++mf)
            #pragma unroll
            for (int r = 0; r < 4; ++r) {
                p[mf][r] = __expf(st[mf][r] - m_new);
                ts += p[mf][r];
            }
        ts += __shfl_xor(ts, 16);
        ts += __shfl_xor(ts, 32);
        l_run = l_run * fac + ts;
        m_run = m_new;

        // --- write P hi/lo (r-quads packed, XOR-swizzled) + fac ---
        #pragma unroll
        for (int mf = 0; mf < 4; ++mf) {
            const int j    = mf * 16 + 4 * gr;
            const int addr = irow * 64 + (j ^ ((irow & 7) << 3));
            ushort h0 = f2bf(p[mf][0]), h1 = f2bf(p[mf][1]);
            ushort h2 = f2bf(p[mf][2]), h3 = f2bf(p[mf][3]);
            ushort l0 = f2bf(p[mf][0] - bf2f(h0)), l1 = f2bf(p[mf][1] - bf2f(h1));
            ushort l2 = f2bf(p[mf][2] - bf2f(h2)), l3 = f2bf(p[mf][3] - bf2f(h3));
            *reinterpret_cast<uint2*>(&Ph[addr]) =
                make_uint2((uint)h0 | ((uint)h1 << 16), (uint)h2 | ((uint)h3 << 16));
            *reinterpret_cast<uint2*>(&Pl[addr]) =
                make_uint2((uint)l0 | ((uint)l1 << 16), (uint)l2 | ((uint)l3 << 16));
        }
        if (gr == 0) fac_sh[irow] = fac;
        __syncthreads();                      // P + fac ready

        // --- rescale accumulators by per-i-strip factor ---
        float fc[4];
        #pragma unroll
        for (int f = 0; f < 4; ++f) fc[f] = fac_sh[f * 16 + m];
        #pragma unroll
        for (int mf = 0; mf < 2; ++mf)
            #pragma unroll
            for (int f = 0; f < 4; ++f)
                #pragma unroll
                for (int r = 0; r < 4; ++r) accv[mf][f][r] *= fc[f];

        // --- PV: out[e][i] += V[e][j] P[i][j]  (3-term hi/lo) ---
        #pragma unroll
        for (int ks = 0; ks < 2; ++ks) {
            bf16x8 pbh[4], pbl[4];
            #pragma unroll
            for (int f = 0; f < 4; ++f) {
                const int i_   = f * 16 + m;
                const int j    = ks * 32 + 8 * gr;
                const int addr = i_ * 64 + (j ^ ((i_ & 7) << 3));
                pbh[f] = *reinterpret_cast<const bf16x8*>(&Ph[addr]);
                pbl[f] = *reinterpret_cast<const bf16x8*>(&Pl[addr]);
            }
            #pragma unroll
            for (int mf = 0; mf < 2; ++mf) {
                const size_t vo = vbase + (size_t)(ebase + mf * 16 + m) * 4096
                                + j0 + ks * 32 + 8 * gr;
                const bf16x8 vah = *(const bf16x8*)(vhp + vo);
                const bf16x8 val = *(const bf16x8*)(vlp + vo);
                #pragma unroll
                for (int f = 0; f < 4; ++f) {
                    accv[mf][f] = __builtin_amdgcn_mfma_f32_16x16x32_bf16(vah, pbh[f], accv[mf][f], 0, 0, 0);
                    accv[mf][f] = __builtin_amdgcn_mfma_f32_16x16x32_bf16(vah, pbl[f], accv[mf][f], 0, 0, 0);
                    accv[mf][f] = __builtin_amdgcn_mfma_f32_16x16x32_bf16(val, pbh[f], accv[mf][f], 0, 0, 0);
                }
            }
        }
        __syncthreads();                      // PV done reading Ph/Pl
    }

    if (gr == 0) l_sh[irow] = l_run;
    __syncthreads();

    const float gv = gamma[0];
    float sc[4];
    #pragma unroll
    for (int f = 0; f < 4; ++f) sc[f] = gv / l_sh[f * 16 + m];
    #pragma unroll
    for (int mf = 0; mf < 2; ++mf)
        #pragma unroll
        for (int f = 0; f < 4; ++f)
            #pragma unroll
            for (int r = 0; r < 4; ++r) {
                const int e = ebase + mf * 16 + 4 * gr + r;
                const int i = i0 + f * 16 + m;
                const size_t idx = ((size_t)b * 256 + e) * 4096 + i;
                out[idx] = accv[mf][f][r] * sc[f] + x[idx];
            }
}

extern "C" void kernel_launch(void* const* d_in, const int* in_sizes, int n_in,
                              void* d_out, int out_size, void* d_ws, size_t ws_size,
                              hipStream_t stream) {
    const float* x     = (const float*)d_in[0];
    const float* wq    = (const float*)d_in[1];
    const float* bq    = (const float*)d_in[2];
    const float* wk    = (const float*)d_in[3];
    const float* bk    = (const float*)d_in[4];
    const float* wv    = (const float*)d_in[5];
    const float* bv    = (const float*)d_in[6];
    const float* gamma = (const float*)d_in[7];
    float* out  = (float*)d_out;
    ushort* ws  = (ushort*)d_ws;    // 10.5M ushorts = 20.97 MB

    proj_kernel<<<256, 256, 0, stream>>>(x, wq, bq, wk, bk, wv, bv, ws);
    attn_kernel<<<512, 256, 0, stream>>>(ws, x, gamma, out);
}